// Round 10
// baseline (54.586 us; speedup 1.0000x reference)
//
#include <hip/hip_runtime.h>
#include <math.h>

// Dims: B=16, H=64, W=64, Cin=3, F=32, K=3
// 4 launches: conv0+prep | conv1 (MFMA) | conv2+pool (MFMA) | tail.
// Tail = conv3 -> LDS(padded 34x34x32 tile) -> conv4+pool -> LDS(16x16x32) ->
// dense(WdT bf16) -> softmax, one block per image (16 blocks x 1024 thr,
// ~89KB dynamic LDS). Convs: bf16 MFMA 16x16x32, A=weights(16 filters),
// B=activations(16 px), K=288; PERMUTED channel layout pi: pos p=8g+j holds
// ch (j<4 ? 4g+j : 16+4g+j-4) so every frag is ONE 16B load; contraction
// cancels pi (A,B share k-order). Activations zero-padded [16][S+2][S+2][32].

typedef __attribute__((ext_vector_type(8))) short bf16x8;
typedef __attribute__((ext_vector_type(4))) float f32x4;

__device__ __align__(16) unsigned short g_wbf[32 * 288];  // bf16 [f][tap*32+pos]

// ---- workspace layout (ushort elems) ----
#define A64e ((size_t)0)
#define B64e ((size_t)(16 * 66 * 66 * 32))            // 2,230,272
#define A32e ((size_t)(2 * 16 * 66 * 66 * 32))        // 4,460,544
#define B32e (A32e + (size_t)(16 * 34 * 34 * 32))     // (unused scratch)
#define Dne  (B32e + (size_t)(16 * 34 * 34 * 32))     // WdT bf16 [10][8192]

__device__ __forceinline__ unsigned short f2bf(float x) {
  union { float f; unsigned u; } v;
  v.f = x;
  return (unsigned short)((v.u + 0x7FFFu + ((v.u >> 16) & 1u)) >> 16);
}
__device__ __forceinline__ float bf2f(unsigned short x) {
  union { unsigned u; float f; } v;
  v.u = ((unsigned)x) << 16;
  return v.f;
}

// ---------------- fused prep + conv0 ----------------------------------------
// blocks 0..511: conv0. blocks 512+: weight convert+permute (1152), pad
// zeroing (12544), WdT bf16 transpose (81920).
__global__ __launch_bounds__(256) void conv0_prep(
    const float* __restrict__ in, const float* __restrict__ W0,
    const float* __restrict__ b0, const float* __restrict__ wsh,
    const float* __restrict__ Wd, unsigned short* __restrict__ ws) {
  if (blockIdx.x >= 512) {  // ---- prep path ----
    int i = (blockIdx.x - 512) * 256 + threadIdx.x;
    if (i < 1152) {  // weight convert: one 16B chunk (8 positions) per thread
      const int o0 = i * 8;
      const int f = o0 / 288;
      const int rem = o0 - f * 288;
      const int tap = rem >> 5;
      const int g = (rem & 31) >> 3;
      unsigned short u[8];
#pragma unroll
      for (int j = 0; j < 8; ++j) {
        const int c = (j < 4) ? 4 * g + j : 16 + 4 * g + (j - 4);
        u[j] = f2bf(wsh[f * 288 + tap * 32 + c]);
      }
      uint4 o;
      o.x = u[0] | ((unsigned)u[1] << 16);
      o.y = u[2] | ((unsigned)u[3] << 16);
      o.z = u[4] | ((unsigned)u[5] << 16);
      o.w = u[6] | ((unsigned)u[7] << 16);
      *(uint4*)(g_wbf + o0) = o;
      return;
    }
    i -= 1152;
    if (i < 12544) {  // each item zeros one 64B chunk of pad cells
      size_t off;
      if (i < 8320) {  // 64-buffers: 4160 items each
        const size_t base = (i < 4160) ? A64e : B64e;
        if (i >= 4160) i -= 4160;
        if (i < 2112) {
          const int b = i / 132, rem = i - b * 132;
          const int rs = rem / 66, ch = rem - rs * 66;
          off = base + (size_t)((b * 66 + (rs ? 65 : 0)) * 66) * 32 + ch * 32;
        } else {
          i -= 2112;
          const int b = i >> 7, rem = i & 127;
          const int r = rem >> 1, side = rem & 1;
          off = base + (size_t)((b * 66 + 1 + r) * 66 + (side ? 65 : 0)) * 32;
        }
      } else {  // A32 pads: 2112 items (+ keep slot math for B32 region unused)
        i -= 8320;
        const size_t base = (i < 2112) ? A32e : B32e;
        if (i >= 2112) i -= 2112;
        if (i < 1088) {
          const int b = i / 68, rem = i - b * 68;
          const int rs = rem / 34, ch = rem - rs * 34;
          off = base + (size_t)((b * 34 + (rs ? 33 : 0)) * 34) * 32 + ch * 32;
        } else {
          i -= 1088;
          const int b = i >> 6, rem = i & 63;
          const int r = rem >> 1, side = rem & 1;
          off = base + (size_t)((b * 34 + 1 + r) * 34 + (side ? 33 : 0)) * 32;
        }
      }
      uint4* p = (uint4*)(ws + off);
      const uint4 z = {0u, 0u, 0u, 0u};
      p[0] = z; p[1] = z; p[2] = z; p[3] = z;
      return;
    }
    i -= 12544;
    if (i < 81920) {  // WdT bf16: WdT[j][q] = Wd[q][j]
      const int j = i >> 13, q = i & 8191;
      ws[Dne + i] = f2bf(Wd[q * 10 + j]);
    }
    return;
  }

  // ---- conv0 path ----
  const int fg = blockIdx.x & 1;
  const int p = (blockIdx.x >> 1) * 256 + threadIdx.x;
  const int b = p >> 12, rem = p & 4095, h = rem >> 6, w = rem & 63;

  float iv[3][3][3];
#pragma unroll
  for (int r = 0; r < 3; ++r) {
    const int hh = h - 1 + r;
    const bool vr = (unsigned)hh < 64u;
#pragma unroll
    for (int j = 0; j < 3; ++j) {
      const int col = w - 1 + j;
      const bool ok = vr && ((unsigned)col < 64u);
      const float* ip = in + (((b << 6) + hh) * 64 + col) * 3;
      iv[r][j][0] = ok ? ip[0] : 0.f;
      iv[r][j][1] = ok ? ip[1] : 0.f;
      iv[r][j][2] = ok ? ip[2] : 0.f;
    }
  }

  float acc[16];
#pragma unroll
  for (int f = 0; f < 16; ++f) acc[f] = b0[fg * 16 + f];

#pragma unroll
  for (int dy = 0; dy < 3; ++dy)
#pragma unroll
    for (int dx = 0; dx < 3; ++dx)
#pragma unroll
      for (int c = 0; c < 3; ++c) {
        const float ival = iv[dy][dx][c];
        const float* wp = W0 + (((dy * 3 + dx) * 3) + c) * 32 + fg * 16;  // s_load
#pragma unroll
        for (int f = 0; f < 16; ++f) acc[f] += ival * wp[f];
      }

  // write permuted: channel fg*16+4g'+r -> position 8g' + 4*fg + r
  unsigned short* op =
      ws + A64e + ((size_t)(b * 66 + 1 + h) * 66 + 1 + w) * 32 + 4 * fg;
#pragma unroll
  for (int gp = 0; gp < 4; ++gp) {
    unsigned short u0 = f2bf(fmaxf(acc[4 * gp + 0], 0.f));
    unsigned short u1 = f2bf(fmaxf(acc[4 * gp + 1], 0.f));
    unsigned short u2 = f2bf(fmaxf(acc[4 * gp + 2], 0.f));
    unsigned short u3 = f2bf(fmaxf(acc[4 * gp + 3], 0.f));
    uint2 o;
    o.x = u0 | ((unsigned)u1 << 16);
    o.y = u2 | ((unsigned)u3 << 16);
    *(uint2*)(op + 8 * gp) = o;
  }
}

// ---------------- MFMA conv 32->32 @64x64 (+ optional fused pool) -----------
template <int LGS, bool POOL, bool OPAD>
__global__ __launch_bounds__(256, 4) void conv_mfma(
    const unsigned short* __restrict__ act, const float* __restrict__ bsh,
    unsigned short* __restrict__ outp) {
  constexpr int S = 1 << LGS, PS = S + 2, LGTC = LGS - 4, TC = S >> 4;
  const int wid = __builtin_amdgcn_readfirstlane((int)(threadIdx.x >> 6));
  const int id = blockIdx.x * 4 + wid;
  const int fhalf = id & 1;
  const int tc = (id >> 1) & (TC - 1);
  const int h2 = (id >> (1 + LGTC)) & ((S >> 1) - 1);
  const int b = id >> (LGS + LGTC);
  const int l = (int)(threadIdx.x & 63);
  const int n = l & 15, g = l >> 4;

  const unsigned short* pA = g_wbf + (fhalf * 16 + n) * 288 + 8 * g;
  bf16x8 af[9];
#pragma unroll
  for (int t = 0; t < 9; ++t) af[t] = *(const bf16x8*)(pA + t * 32);

  const unsigned short* pB =
      act + ((size_t)(b * PS + 2 * h2) * PS + tc * 16 + n) * 32 + 8 * g;
  bf16x8 bfr[4][3];
#pragma unroll
  for (int rr = 0; rr < 4; ++rr)
#pragma unroll
    for (int dx = 0; dx < 3; ++dx)
      bfr[rr][dx] = *(const bf16x8*)(pB + (rr * PS + dx) * 32);

  f32x4 acc0 = {0.f, 0.f, 0.f, 0.f};
  f32x4 acc1 = {0.f, 0.f, 0.f, 0.f};
#pragma unroll
  for (int tap = 0; tap < 9; ++tap) {
    const int dy = tap / 3, dx = tap - dy * 3;
    acc0 = __builtin_amdgcn_mfma_f32_16x16x32_bf16(af[tap], bfr[dy][dx], acc0, 0, 0, 0);
    acc1 = __builtin_amdgcn_mfma_f32_16x16x32_bf16(af[tap], bfr[dy + 1][dx], acc1, 0, 0, 0);
  }

  const float4 bias = *(const float4*)(bsh + fhalf * 16 + 4 * g);
  const float bv[4] = {bias.x, bias.y, bias.z, bias.w};
  const int opos = 8 * g + 4 * fhalf;

  if (!POOL) {
#pragma unroll
    for (int t = 0; t < 2; ++t) {
      unsigned short u[4];
#pragma unroll
      for (int r = 0; r < 4; ++r) {
        const float a = (t == 0) ? acc0[r] : acc1[r];
        u[r] = f2bf(fmaxf(a + bv[r], 0.f));
      }
      uint2 o;
      o.x = u[0] | ((unsigned)u[1] << 16);
      o.y = u[2] | ((unsigned)u[3] << 16);
      unsigned short* op = outp +
          ((size_t)(b * PS + 2 * h2 + 1 + t) * PS + 1 + tc * 16 + n) * 32 + opos;
      *(uint2*)op = o;
    }
  } else {
    float m[4];
#pragma unroll
    for (int r = 0; r < 4; ++r) {
      const float v0 = fmaxf(acc0[r] + bv[r], 0.f);
      const float v1 = fmaxf(acc1[r] + bv[r], 0.f);
      m[r] = fmaxf(v0, v1);
      m[r] = fmaxf(m[r], __shfl_xor(m[r], 1, 64));
    }
    if (!(n & 1)) {
      unsigned short u[4];
#pragma unroll
      for (int r = 0; r < 4; ++r) u[r] = f2bf(m[r]);
      uint2 o;
      o.x = u[0] | ((unsigned)u[1] << 16);
      o.y = u[2] | ((unsigned)u[3] << 16);
      unsigned short* op =
          outp + ((size_t)(b * 34 + 1 + h2) * 34 + 1 + tc * 8 + (n >> 1)) * 32 + opos;
      *(uint2*)op = o;
    }
  }
}

// ------- tail: conv3 -> LDS -> conv4+pool -> LDS -> dense -> softmax --------
// one block per image; 1024 threads = 16 waves. conv3-out LDS layout:
// [row 34][chunk g 4][px 34][8ch] bf16 (frag read = 1 ds_read_b128).
__global__ __launch_bounds__(1024) void tail(
    const unsigned short* __restrict__ A32, const float* __restrict__ bsh,
    const unsigned short* __restrict__ wdt, const float* __restrict__ bd,
    float* __restrict__ out) {
  extern __shared__ unsigned short lds[];
  unsigned short* t3 = lds;                    // 34*4*34*8 = 36992 ush (74KB)
  unsigned short* dn = lds + 36992;            // 16*16*32 = 8192 ush (16KB)
  float* red = (float*)(lds + 36992 + 8192);   // [16][10] f32

  const int b = blockIdx.x;
  const int tid = threadIdx.x;
  const int wid = __builtin_amdgcn_readfirstlane(tid >> 6);  // 0..15
  const int l = tid & 63;
  const int n = l & 15, g = l >> 4;
  const int fhalf = wid & 1;  // conv3 AND conv4 filter half (shared weights)

  // A-frags once per wave (reused by conv3 and conv4)
  const unsigned short* pA = g_wbf + (fhalf * 16 + n) * 288 + 8 * g;
  bf16x8 af[9];
#pragma unroll
  for (int t = 0; t < 9; ++t) af[t] = *(const bf16x8*)(pA + t * 32);

  const float4 bias = *(const float4*)(bsh + fhalf * 16 + 4 * g);
  const float bv[4] = {bias.x, bias.y, bias.z, bias.w};
  const int opos = 8 * g + 4 * fhalf;

  // zero the pad cells of the conv3-out tile (528 x 16B)
  if (tid < 528) {
    const int c = tid >> 2, chunk = tid & 3;
    int row, px;
    if (c < 68) { row = (c >= 34) ? 33 : 0; px = (c >= 34) ? c - 34 : c; }
    else { const int c2 = c - 68; row = 1 + (c2 >> 1); px = (c2 & 1) ? 33 : 0; }
    uint4* p = (uint4*)(t3 + ((row * 4 + chunk) * 34 + px) * 8);
    const uint4 z = {0u, 0u, 0u, 0u};
    *p = z;
  }
  __syncthreads();

  // ---- conv3: 64 wave-units (fhalf, tc, h2), 4 per wave ----
#pragma unroll
  for (int u = 0; u < 4; ++u) {
    const int idx = ((wid >> 1) << 2) + u;  // 0..31
    const int h2 = idx >> 1, tc = idx & 1;
    const unsigned short* pB =
        A32 + ((size_t)(b * 34 + 2 * h2) * 34 + tc * 16 + n) * 32 + 8 * g;
    bf16x8 bfr[4][3];
#pragma unroll
    for (int rr = 0; rr < 4; ++rr)
#pragma unroll
      for (int dx = 0; dx < 3; ++dx)
        bfr[rr][dx] = *(const bf16x8*)(pB + (rr * 34 + dx) * 32);

    f32x4 acc0 = {0.f, 0.f, 0.f, 0.f};
    f32x4 acc1 = {0.f, 0.f, 0.f, 0.f};
#pragma unroll
    for (int tap = 0; tap < 9; ++tap) {
      const int dy = tap / 3, dx = tap - dy * 3;
      acc0 = __builtin_amdgcn_mfma_f32_16x16x32_bf16(af[tap], bfr[dy][dx], acc0, 0, 0, 0);
      acc1 = __builtin_amdgcn_mfma_f32_16x16x32_bf16(af[tap], bfr[dy + 1][dx], acc1, 0, 0, 0);
    }
    // write 2 rows into LDS tile: row = 2h2+1+t, px = 1 + tc*16 + n,
    // chunk = g, ushort offset within chunk = 4*fhalf
#pragma unroll
    for (int t = 0; t < 2; ++t) {
      unsigned short uu[4];
#pragma unroll
      for (int r = 0; r < 4; ++r) {
        const float a = (t == 0) ? acc0[r] : acc1[r];
        uu[r] = f2bf(fmaxf(a + bv[r], 0.f));
      }
      uint2 o;
      o.x = uu[0] | ((unsigned)uu[1] << 16);
      o.y = uu[2] | ((unsigned)uu[3] << 16);
      *(uint2*)(t3 + (((2 * h2 + 1 + t) * 4 + g) * 34 + 1 + tc * 16 + n) * 8 +
                4 * fhalf) = o;
    }
  }
  __syncthreads();

  // ---- conv4 + pool: 64 wave-units, 4 per wave; B-frags from LDS ----
#pragma unroll
  for (int u = 0; u < 4; ++u) {
    const int idx = ((wid >> 1) << 2) + u;
    const int h2 = idx >> 1, tc = idx & 1;
    bf16x8 bfr[4][3];
#pragma unroll
    for (int rr = 0; rr < 4; ++rr)
#pragma unroll
      for (int dx = 0; dx < 3; ++dx)
        bfr[rr][dx] = *(const bf16x8*)(
            t3 + (((2 * h2 + rr) * 4 + g) * 34 + tc * 16 + n + dx) * 8);

    f32x4 acc0 = {0.f, 0.f, 0.f, 0.f};
    f32x4 acc1 = {0.f, 0.f, 0.f, 0.f};
#pragma unroll
    for (int tap = 0; tap < 9; ++tap) {
      const int dy = tap / 3, dx = tap - dy * 3;
      acc0 = __builtin_amdgcn_mfma_f32_16x16x32_bf16(af[tap], bfr[dy][dx], acc0, 0, 0, 0);
      acc1 = __builtin_amdgcn_mfma_f32_16x16x32_bf16(af[tap], bfr[dy + 1][dx], acc1, 0, 0, 0);
    }
    float m[4];
#pragma unroll
    for (int r = 0; r < 4; ++r) {
      const float v0 = fmaxf(acc0[r] + bv[r], 0.f);
      const float v1 = fmaxf(acc1[r] + bv[r], 0.f);
      m[r] = fmaxf(v0, v1);
      m[r] = fmaxf(m[r], __shfl_xor(m[r], 1, 64));
    }
    if (!(n & 1)) {
      unsigned short uu[4];
#pragma unroll
      for (int r = 0; r < 4; ++r) uu[r] = f2bf(m[r]);
      uint2 o;
      o.x = uu[0] | ((unsigned)uu[1] << 16);
      o.y = uu[2] | ((unsigned)uu[3] << 16);
      // UNpermuted NHWC (16x16x32): row h2, col tc*8 + n/2, ch fhalf*16+4g
      *(uint2*)(dn + ((h2 * 16) + tc * 8 + (n >> 1)) * 32 + fhalf * 16 + 4 * g) = o;
    }
  }
  __syncthreads();

  // ---- dense 8192->10 + softmax (x in LDS, WdT bf16 [10][8192]) ----
  float acc[10];
#pragma unroll
  for (int j = 0; j < 10; ++j) acc[j] = 0.f;
#pragma unroll
  for (int it = 0; it < 8; ++it) {
    const int q = it * 1024 + tid;
    const float xv = bf2f(dn[q]);
#pragma unroll
    for (int j = 0; j < 10; ++j) acc[j] += xv * bf2f(wdt[j * 8192 + q]);
  }
#pragma unroll
  for (int off = 32; off > 0; off >>= 1)
#pragma unroll
    for (int j = 0; j < 10; ++j) acc[j] += __shfl_down(acc[j], off, 64);
  if (l == 0) {
#pragma unroll
    for (int j = 0; j < 10; ++j) red[wid * 10 + j] = acc[j];
  }
  __syncthreads();
  if (tid == 0) {
    float lg[10];
    float mx = -1e30f;
#pragma unroll
    for (int j = 0; j < 10; ++j) {
      float s = 0.f;
#pragma unroll
      for (int w = 0; w < 16; ++w) s += red[w * 10 + j];
      lg[j] = s + bd[j];
      mx = fmaxf(mx, lg[j]);
    }
    float s = 0.f;
#pragma unroll
    for (int j = 0; j < 10; ++j) {
      lg[j] = expf(lg[j] - mx);
      s += lg[j];
    }
    const float inv = 1.f / s;
#pragma unroll
    for (int j = 0; j < 10; ++j) out[b * 10 + j] = lg[j] * inv;
  }
}

extern "C" void kernel_launch(void* const* d_in, const int* in_sizes, int n_in,
                              void* d_out, int out_size, void* d_ws, size_t ws_size,
                              hipStream_t stream) {
  const float* in = (const float*)d_in[0];
  const float* W0 = (const float*)d_in[1];
  const float* b0 = (const float*)d_in[2];
  const float* wsh = (const float*)d_in[3];
  const float* bsh = (const float*)d_in[4];
  const float* Wd = (const float*)d_in[5];
  const float* bd = (const float*)d_in[6];
  float* out = (float*)d_out;

  unsigned short* ws = (unsigned short*)d_ws;
  unsigned short* A64 = ws + A64e;
  unsigned short* B64 = ws + B64e;
  unsigned short* A32 = ws + A32e;
  unsigned short* WdT = ws + Dne;

  const int tail_lds = (36992 + 8192) * 2 + 16 * 10 * 4;  // 91008 B
  static bool attr_set = false;
  if (!attr_set) {
    hipFuncSetAttribute((const void*)tail,
                        hipFuncAttributeMaxDynamicSharedMemorySize, tail_lds);
    attr_set = true;
  }

  conv0_prep<<<886, 256, 0, stream>>>(in, W0, b0, wsh, Wd, ws);
  conv_mfma<6, false, false><<<1024, 256, 0, stream>>>(A64, bsh, B64);  // conv1
  conv_mfma<6, true, true><<<1024, 256, 0, stream>>>(B64, bsh, A32);    // conv2+pool
  tail<<<16, 1024, tail_lds, stream>>>(A32, bsh, WdT, bd, out);
}

// Round 11
// 48.228 us; speedup vs baseline: 1.1318x; 1.1318x over previous
//
#include <hip/hip_runtime.h>
#include <math.h>

// Dims: B=16, H=64, W=64, Cin=3, F=32, K=3
// 4 launches: conv0+prep | conv1 (MFMA) | conv2+pool (MFMA) | conv34_dense.
// conv34_dense: 32 blocks x 512 thr (8 waves, VGPR<=256). Block = (image,
// row-half): conv3 on 18 rows (1-row halo recompute) -> 20-row padded LDS
// tile -> conv4+pool for its 8 output rows -> partial dense (contiguous 4096
// flatten slice) -> fp32 atomicAdd logits -> last block (device counter +
// threadfence) does bias+softmax. prep zeroes logits+counter every launch.
// Convs: bf16 MFMA 16x16x32, A=weights(16 filters), B=activations(16 px),
// K=288; PERMUTED channel layout pi (pos 8g+j <-> ch j<4?4g+j:16+4g+j-4) so
// every frag is ONE 16B load; contraction cancels pi. Activations zero-padded
// [16][S+2][S+2][32] bf16.

typedef __attribute__((ext_vector_type(8))) short bf16x8;
typedef __attribute__((ext_vector_type(4))) float f32x4;

__device__ __align__(16) unsigned short g_wbf[32 * 288];  // bf16 [f][tap*32+pos]

// ---- workspace layout (ushort elems) ----
#define A64e ((size_t)0)
#define B64e ((size_t)(16 * 66 * 66 * 32))            // 2,230,272
#define A32e ((size_t)(2 * 16 * 66 * 66 * 32))        // 4,460,544
#define B32e (A32e + (size_t)(16 * 34 * 34 * 32))     // (scratch, unused)
#define Dne  (B32e + (size_t)(16 * 34 * 34 * 32))     // WdT bf16 [10][8192]
#define LGe  (Dne + (size_t)81920)                    // logits f32[160] + cnt

__device__ __forceinline__ unsigned short f2bf(float x) {
  union { float f; unsigned u; } v;
  v.f = x;
  return (unsigned short)((v.u + 0x7FFFu + ((v.u >> 16) & 1u)) >> 16);
}
__device__ __forceinline__ float bf2f(unsigned short x) {
  union { unsigned u; float f; } v;
  v.u = ((unsigned)x) << 16;
  return v.f;
}

// ---------------- fused prep + conv0 ----------------------------------------
__global__ __launch_bounds__(256) void conv0_prep(
    const float* __restrict__ in, const float* __restrict__ W0,
    const float* __restrict__ b0, const float* __restrict__ wsh,
    const float* __restrict__ Wd, unsigned short* __restrict__ ws) {
  if (blockIdx.x >= 512) {  // ---- prep path ----
    int i = (blockIdx.x - 512) * 256 + threadIdx.x;
    if (i < 1152) {  // weight convert+permute: one 16B chunk per thread
      const int o0 = i * 8;
      const int f = o0 / 288;
      const int rem = o0 - f * 288;
      const int tap = rem >> 5;
      const int g = (rem & 31) >> 3;
      unsigned short u[8];
#pragma unroll
      for (int j = 0; j < 8; ++j) {
        const int c = (j < 4) ? 4 * g + j : 16 + 4 * g + (j - 4);
        u[j] = f2bf(wsh[f * 288 + tap * 32 + c]);
      }
      uint4 o;
      o.x = u[0] | ((unsigned)u[1] << 16);
      o.y = u[2] | ((unsigned)u[3] << 16);
      o.z = u[4] | ((unsigned)u[5] << 16);
      o.w = u[6] | ((unsigned)u[7] << 16);
      *(uint4*)(g_wbf + o0) = o;
      return;
    }
    i -= 1152;
    if (i < 12544) {  // each item zeros one 64B chunk of pad cells
      size_t off;
      if (i < 8320) {  // 64-buffers: 4160 items each
        const size_t base = (i < 4160) ? A64e : B64e;
        if (i >= 4160) i -= 4160;
        if (i < 2112) {
          const int b = i / 132, rem = i - b * 132;
          const int rs = rem / 66, ch = rem - rs * 66;
          off = base + (size_t)((b * 66 + (rs ? 65 : 0)) * 66) * 32 + ch * 32;
        } else {
          i -= 2112;
          const int b = i >> 7, rem = i & 127;
          const int r = rem >> 1, side = rem & 1;
          off = base + (size_t)((b * 66 + 1 + r) * 66 + (side ? 65 : 0)) * 32;
        }
      } else {
        i -= 8320;
        const size_t base = (i < 2112) ? A32e : B32e;
        if (i >= 2112) i -= 2112;
        if (i < 1088) {
          const int b = i / 68, rem = i - b * 68;
          const int rs = rem / 34, ch = rem - rs * 34;
          off = base + (size_t)((b * 34 + (rs ? 33 : 0)) * 34) * 32 + ch * 32;
        } else {
          i -= 1088;
          const int b = i >> 6, rem = i & 63;
          const int r = rem >> 1, side = rem & 1;
          off = base + (size_t)((b * 34 + 1 + r) * 34 + (side ? 33 : 0)) * 32;
        }
      }
      uint4* p = (uint4*)(ws + off);
      const uint4 z = {0u, 0u, 0u, 0u};
      p[0] = z; p[1] = z; p[2] = z; p[3] = z;
      return;
    }
    i -= 12544;
    if (i < 81920) {  // WdT bf16: WdT[j][q] = Wd[q][j]
      const int j = i >> 13, q = i & 8191;
      ws[Dne + i] = f2bf(Wd[q * 10 + j]);
      return;
    }
    i -= 81920;
    if (i < 161) ((unsigned*)(ws + LGe))[i] = 0u;  // logits[160] + counter
    return;
  }

  // ---- conv0 path ----
  const int fg = blockIdx.x & 1;
  const int p = (blockIdx.x >> 1) * 256 + threadIdx.x;
  const int b = p >> 12, rem = p & 4095, h = rem >> 6, w = rem & 63;

  float iv[3][3][3];
#pragma unroll
  for (int r = 0; r < 3; ++r) {
    const int hh = h - 1 + r;
    const bool vr = (unsigned)hh < 64u;
#pragma unroll
    for (int j = 0; j < 3; ++j) {
      const int col = w - 1 + j;
      const bool ok = vr && ((unsigned)col < 64u);
      const float* ip = in + (((b << 6) + hh) * 64 + col) * 3;
      iv[r][j][0] = ok ? ip[0] : 0.f;
      iv[r][j][1] = ok ? ip[1] : 0.f;
      iv[r][j][2] = ok ? ip[2] : 0.f;
    }
  }

  float acc[16];
#pragma unroll
  for (int f = 0; f < 16; ++f) acc[f] = b0[fg * 16 + f];

#pragma unroll
  for (int dy = 0; dy < 3; ++dy)
#pragma unroll
    for (int dx = 0; dx < 3; ++dx)
#pragma unroll
      for (int c = 0; c < 3; ++c) {
        const float ival = iv[dy][dx][c];
        const float* wp = W0 + (((dy * 3 + dx) * 3) + c) * 32 + fg * 16;  // s_load
#pragma unroll
        for (int f = 0; f < 16; ++f) acc[f] += ival * wp[f];
      }

  unsigned short* op =
      ws + A64e + ((size_t)(b * 66 + 1 + h) * 66 + 1 + w) * 32 + 4 * fg;
#pragma unroll
  for (int gp = 0; gp < 4; ++gp) {
    unsigned short u0 = f2bf(fmaxf(acc[4 * gp + 0], 0.f));
    unsigned short u1 = f2bf(fmaxf(acc[4 * gp + 1], 0.f));
    unsigned short u2 = f2bf(fmaxf(acc[4 * gp + 2], 0.f));
    unsigned short u3 = f2bf(fmaxf(acc[4 * gp + 3], 0.f));
    uint2 o;
    o.x = u0 | ((unsigned)u1 << 16);
    o.y = u2 | ((unsigned)u3 << 16);
    *(uint2*)(op + 8 * gp) = o;
  }
}

// ---------------- MFMA conv 32->32 @64x64 (+ optional fused pool) -----------
template <int LGS, bool POOL, bool OPAD>
__global__ __launch_bounds__(256, 4) void conv_mfma(
    const unsigned short* __restrict__ act, const float* __restrict__ bsh,
    unsigned short* __restrict__ outp) {
  constexpr int S = 1 << LGS, PS = S + 2, LGTC = LGS - 4, TC = S >> 4;
  const int wid = __builtin_amdgcn_readfirstlane((int)(threadIdx.x >> 6));
  const int id = blockIdx.x * 4 + wid;
  const int fhalf = id & 1;
  const int tc = (id >> 1) & (TC - 1);
  const int h2 = (id >> (1 + LGTC)) & ((S >> 1) - 1);
  const int b = id >> (LGS + LGTC);
  const int l = (int)(threadIdx.x & 63);
  const int n = l & 15, g = l >> 4;

  const unsigned short* pA = g_wbf + (fhalf * 16 + n) * 288 + 8 * g;
  bf16x8 af[9];
#pragma unroll
  for (int t = 0; t < 9; ++t) af[t] = *(const bf16x8*)(pA + t * 32);

  const unsigned short* pB =
      act + ((size_t)(b * PS + 2 * h2) * PS + tc * 16 + n) * 32 + 8 * g;
  bf16x8 bfr[4][3];
#pragma unroll
  for (int rr = 0; rr < 4; ++rr)
#pragma unroll
    for (int dx = 0; dx < 3; ++dx)
      bfr[rr][dx] = *(const bf16x8*)(pB + (rr * PS + dx) * 32);

  f32x4 acc0 = {0.f, 0.f, 0.f, 0.f};
  f32x4 acc1 = {0.f, 0.f, 0.f, 0.f};
#pragma unroll
  for (int tap = 0; tap < 9; ++tap) {
    const int dy = tap / 3, dx = tap - dy * 3;
    acc0 = __builtin_amdgcn_mfma_f32_16x16x32_bf16(af[tap], bfr[dy][dx], acc0, 0, 0, 0);
    acc1 = __builtin_amdgcn_mfma_f32_16x16x32_bf16(af[tap], bfr[dy + 1][dx], acc1, 0, 0, 0);
  }

  const float4 bias = *(const float4*)(bsh + fhalf * 16 + 4 * g);
  const float bv[4] = {bias.x, bias.y, bias.z, bias.w};
  const int opos = 8 * g + 4 * fhalf;

  if (!POOL) {
#pragma unroll
    for (int t = 0; t < 2; ++t) {
      unsigned short u[4];
#pragma unroll
      for (int r = 0; r < 4; ++r) {
        const float a = (t == 0) ? acc0[r] : acc1[r];
        u[r] = f2bf(fmaxf(a + bv[r], 0.f));
      }
      uint2 o;
      o.x = u[0] | ((unsigned)u[1] << 16);
      o.y = u[2] | ((unsigned)u[3] << 16);
      unsigned short* op = outp +
          ((size_t)(b * PS + 2 * h2 + 1 + t) * PS + 1 + tc * 16 + n) * 32 + opos;
      *(uint2*)op = o;
    }
  } else {
    float m[4];
#pragma unroll
    for (int r = 0; r < 4; ++r) {
      const float v0 = fmaxf(acc0[r] + bv[r], 0.f);
      const float v1 = fmaxf(acc1[r] + bv[r], 0.f);
      m[r] = fmaxf(v0, v1);
      m[r] = fmaxf(m[r], __shfl_xor(m[r], 1, 64));
    }
    if (!(n & 1)) {
      unsigned short u[4];
#pragma unroll
      for (int r = 0; r < 4; ++r) u[r] = f2bf(m[r]);
      uint2 o;
      o.x = u[0] | ((unsigned)u[1] << 16);
      o.y = u[2] | ((unsigned)u[3] << 16);
      unsigned short* op =
          outp + ((size_t)(b * 34 + 1 + h2) * 34 + 1 + tc * 8 + (n >> 1)) * 32 + opos;
      *(uint2*)op = o;
    }
  }
}

// ---- conv34_dense: 32 blocks x 512 thr; block = (image, row-half) ---------
__global__ __launch_bounds__(512, 2) void conv34_dense(
    const unsigned short* __restrict__ A32, const float* __restrict__ bsh,
    const unsigned short* __restrict__ wdt, const float* __restrict__ bd,
    float* __restrict__ logits, int* __restrict__ cnt,
    float* __restrict__ out) {
  __shared__ unsigned short t3[20 * 4 * 34 * 8];  // 43.5KB padded conv3 tile
  __shared__ unsigned short dn[4096];             // 8KB: 8 rows x 16 x 32
  __shared__ float red[8 * 10];
  __shared__ float sm[160];
  __shared__ int lastflag;

  const int img = blockIdx.x >> 1;
  const int half = blockIdx.x & 1;
  const int tid = threadIdx.x;
  const int wid = __builtin_amdgcn_readfirstlane(tid >> 6);  // 0..7
  const int l = tid & 63;
  const int n = l & 15, g = l >> 4;
  const int fhalf = wid & 1;
  const int k0 = wid >> 1;  // 0..3

  // tile row tr <-> conv3 row r3 = half*16 - 2 + tr (tr in [0,20))
  const int r3s = half ? 14 : 0;       // first computed conv3 row
  const int troff = 2 - half * 16;     // tr = r3 + troff

  // A-frags + bias (conv3 and conv4 share weights)
  const unsigned short* pA = g_wbf + (fhalf * 16 + n) * 288 + 8 * g;
  bf16x8 af[9];
#pragma unroll
  for (int t = 0; t < 9; ++t) af[t] = *(const bf16x8*)(pA + t * 32);
  const float4 bias = *(const float4*)(bsh + fhalf * 16 + 4 * g);
  const float bv[4] = {bias.x, bias.y, bias.z, bias.w};

  // zero pad cells: halo row (r3 = -1 or 32) + px 0/33 for tr 1..18
  if (tid < 280) {
    int tr, gg, px;
    if (tid < 136) {
      tr = half ? 18 : 1;
      gg = tid / 34;
      px = tid - gg * 34;
    } else {
      const int c2 = tid - 136;
      tr = 1 + (c2 >> 3);
      const int rem = c2 & 7;
      gg = rem >> 1;
      px = (rem & 1) ? 33 : 0;
    }
    const uint4 z = {0u, 0u, 0u, 0u};
    *(uint4*)(t3 + ((tr * 4 + gg) * 34 + px) * 8) = z;
  }

  // ---- conv3: 18 rows (9 pairs) x 2 tc, per-fhalf -> 18 units / 4 waves ----
  for (int k = k0; k < 18; k += 4) {
    const int pair = k >> 1, tc = k & 1;
    const int r3p = r3s + 2 * pair;
    const unsigned short* pB =
        A32 + ((size_t)(img * 34 + r3p) * 34 + tc * 16 + n) * 32 + 8 * g;
    bf16x8 bfr[4][3];
#pragma unroll
    for (int rr = 0; rr < 4; ++rr)
#pragma unroll
      for (int dx = 0; dx < 3; ++dx)
        bfr[rr][dx] = *(const bf16x8*)(pB + (rr * 34 + dx) * 32);

    f32x4 acc0 = {0.f, 0.f, 0.f, 0.f};
    f32x4 acc1 = {0.f, 0.f, 0.f, 0.f};
#pragma unroll
    for (int tap = 0; tap < 9; ++tap) {
      const int dy = tap / 3, dx = tap - dy * 3;
      acc0 = __builtin_amdgcn_mfma_f32_16x16x32_bf16(af[tap], bfr[dy][dx], acc0, 0, 0, 0);
      acc1 = __builtin_amdgcn_mfma_f32_16x16x32_bf16(af[tap], bfr[dy + 1][dx], acc1, 0, 0, 0);
    }
#pragma unroll
    for (int t = 0; t < 2; ++t) {
      const int tr = r3p + t + troff;  // in [0,20)
      unsigned short uu[4];
#pragma unroll
      for (int r = 0; r < 4; ++r) {
        const float a = (t == 0) ? acc0[r] : acc1[r];
        uu[r] = f2bf(fmaxf(a + bv[r], 0.f));
      }
      uint2 o;
      o.x = uu[0] | ((unsigned)uu[1] << 16);
      o.y = uu[2] | ((unsigned)uu[3] << 16);
      *(uint2*)(t3 + ((tr * 4 + g) * 34 + 1 + tc * 16 + n) * 8 + 4 * fhalf) = o;
    }
  }
  __syncthreads();

  // ---- conv4 + pool: 8 row-pairs x 2 tc per fhalf -> 16 units / 4 waves ----
  for (int k = k0; k < 16; k += 4) {
    const int h2 = k >> 1, tc = k & 1;
    bf16x8 bfr[4][3];
#pragma unroll
    for (int rr = 0; rr < 4; ++rr)
#pragma unroll
      for (int dx = 0; dx < 3; ++dx)
        bfr[rr][dx] = *(const bf16x8*)(
            t3 + (((2 * h2 + 1 + rr) * 4 + g) * 34 + tc * 16 + n + dx) * 8);

    f32x4 acc0 = {0.f, 0.f, 0.f, 0.f};
    f32x4 acc1 = {0.f, 0.f, 0.f, 0.f};
#pragma unroll
    for (int tap = 0; tap < 9; ++tap) {
      const int dy = tap / 3, dx = tap - dy * 3;
      acc0 = __builtin_amdgcn_mfma_f32_16x16x32_bf16(af[tap], bfr[dy][dx], acc0, 0, 0, 0);
      acc1 = __builtin_amdgcn_mfma_f32_16x16x32_bf16(af[tap], bfr[dy + 1][dx], acc1, 0, 0, 0);
    }
    float m[4];
#pragma unroll
    for (int r = 0; r < 4; ++r) {
      const float v0 = fmaxf(acc0[r] + bv[r], 0.f);
      const float v1 = fmaxf(acc1[r] + bv[r], 0.f);
      m[r] = fmaxf(v0, v1);
      m[r] = fmaxf(m[r], __shfl_xor(m[r], 1, 64));
    }
    if (!(n & 1)) {
      unsigned short uu[4];
#pragma unroll
      for (int r = 0; r < 4; ++r) uu[r] = f2bf(m[r]);
      uint2 o;
      o.x = uu[0] | ((unsigned)uu[1] << 16);
      o.y = uu[2] | ((unsigned)uu[3] << 16);
      // UNpermuted: row h2 (local), col tc*8 + n/2, ch fhalf*16 + 4g
      *(uint2*)(dn + ((h2 * 16) + tc * 8 + (n >> 1)) * 32 + fhalf * 16 + 4 * g) = o;
    }
  }
  __syncthreads();

  // ---- partial dense over this half's contiguous 4096 flatten slice -------
  float acc[10];
#pragma unroll
  for (int j = 0; j < 10; ++j) acc[j] = 0.f;
#pragma unroll
  for (int it = 0; it < 8; ++it) {
    const int q = it * 512 + tid;
    const float xv = bf2f(dn[q]);
    const unsigned short* wr = wdt + half * 4096 + q;
#pragma unroll
    for (int j = 0; j < 10; ++j) acc[j] += xv * bf2f(wr[j * 8192]);
  }
#pragma unroll
  for (int off = 32; off > 0; off >>= 1)
#pragma unroll
    for (int j = 0; j < 10; ++j) acc[j] += __shfl_down(acc[j], off, 64);
  if (l == 0) {
#pragma unroll
    for (int j = 0; j < 10; ++j) red[wid * 10 + j] = acc[j];
  }
  __syncthreads();
  if (tid < 10) {
    float s = 0.f;
#pragma unroll
    for (int w = 0; w < 8; ++w) s += red[w * 10 + tid];
    atomicAdd(logits + img * 10 + tid, s);
    __threadfence();
  }
  __syncthreads();
  if (tid == 0) {
    const int old = atomicAdd(cnt, 1);
    lastflag = (old == 31) ? 1 : 0;
  }
  __syncthreads();

  // ---- last block: bias + softmax for all 16 images ----
  if (lastflag) {
    if (tid < 160) {
      const int j = tid - (tid / 10) * 10;
      sm[tid] = atomicAdd(logits + tid, 0.f) + bd[j];
    }
    __syncthreads();
    if (tid < 16) {
      float lg[10];
      float mx = -1e30f;
#pragma unroll
      for (int j = 0; j < 10; ++j) {
        lg[j] = sm[tid * 10 + j];
        mx = fmaxf(mx, lg[j]);
      }
      float s = 0.f;
#pragma unroll
      for (int j = 0; j < 10; ++j) {
        lg[j] = expf(lg[j] - mx);
        s += lg[j];
      }
      const float inv = 1.f / s;
#pragma unroll
      for (int j = 0; j < 10; ++j) out[tid * 10 + j] = lg[j] * inv;
    }
  }
}

extern "C" void kernel_launch(void* const* d_in, const int* in_sizes, int n_in,
                              void* d_out, int out_size, void* d_ws, size_t ws_size,
                              hipStream_t stream) {
  const float* in = (const float*)d_in[0];
  const float* W0 = (const float*)d_in[1];
  const float* b0 = (const float*)d_in[2];
  const float* wsh = (const float*)d_in[3];
  const float* bsh = (const float*)d_in[4];
  const float* Wd = (const float*)d_in[5];
  const float* bd = (const float*)d_in[6];
  float* out = (float*)d_out;

  unsigned short* ws = (unsigned short*)d_ws;
  unsigned short* A64 = ws + A64e;
  unsigned short* B64 = ws + B64e;
  unsigned short* A32 = ws + A32e;
  unsigned short* WdT = ws + Dne;
  float* logits = (float*)(ws + LGe);
  int* cnt = (int*)(logits + 160);

  conv0_prep<<<887, 256, 0, stream>>>(in, W0, b0, wsh, Wd, ws);
  conv_mfma<6, false, false><<<1024, 256, 0, stream>>>(A64, bsh, B64);  // conv1
  conv_mfma<6, true, true><<<1024, 256, 0, stream>>>(B64, bsh, A32);    // conv2+pool
  conv34_dense<<<32, 512, 0, stream>>>(A32, bsh, WdT, bd, logits, cnt, out);
}

// Round 12
// 41.464 us; speedup vs baseline: 1.3165x; 1.1631x over previous
//
#include <hip/hip_runtime.h>
#include <math.h>

// Dims: B=16, H=64, W=64, Cin=3, F=32, K=3
// 5 launches: conv0+prep | conv1 | conv2+pool | conv3 | conv4+pool+dense+softmax.
// Convs 1-4: bf16 MFMA 16x16x32, A=weights(16 filters), B=activations(16 px),
// K=288; PERMUTED channel layout pi (pos 8g+j <-> ch j<4?4g+j:16+4g+j-4) so
// every frag is ONE 16B load; contraction cancels pi (A,B share k-order).
// Activations zero-padded [16][S+2][S+2][32] bf16 -> unconditional halo loads.
// conv4 keeps 256 blocks (1024 wave-units) and fuses dense via per-lane
// partials (Wd2 bf16 [8192][16] rows) + wave shfl reduce + 10 atomicAdds per
// block + R11-proven counter/lastflag softmax. conv0: 4-way filter split +
// zero-page tap pointers (unconditional loads, fewer cndmask chains).

typedef __attribute__((ext_vector_type(8))) short bf16x8;
typedef __attribute__((ext_vector_type(4))) float f32x4;

__device__ __align__(16) unsigned short g_wbf[32 * 288];  // bf16 [f][tap*32+pos]
__device__ __align__(64) float g_zerof[16];               // zero page (floats)

// ---- workspace layout (ushort elems) ----
#define A64e ((size_t)0)
#define B64e ((size_t)(16 * 66 * 66 * 32))            // 2,230,272
#define A32e ((size_t)(2 * 16 * 66 * 66 * 32))        // 4,460,544
#define B32e (A32e + (size_t)(16 * 34 * 34 * 32))     // 5,052,416
#define Dne  (B32e + (size_t)(16 * 34 * 34 * 32))     // Wd2 bf16 [8192][16]
#define LGe  (Dne + (size_t)131072)                   // logits f32[160] + cnt

__device__ __forceinline__ unsigned short f2bf(float x) {
  union { float f; unsigned u; } v;
  v.f = x;
  return (unsigned short)((v.u + 0x7FFFu + ((v.u >> 16) & 1u)) >> 16);
}
__device__ __forceinline__ float bf2f(unsigned short x) {
  union { unsigned u; float f; } v;
  v.u = ((unsigned)x) << 16;
  return v.f;
}

// ---------------- fused prep + conv0 ----------------------------------------
// blocks 0..1023: conv0 (fg = blockIdx&3, 8 filters each).
// blocks 1024+: w convert+permute (1152) | pad zero (12544) | Wd2 (131072) |
// logits+cnt zero (161).
__global__ __launch_bounds__(256) void conv0_prep(
    const float* __restrict__ in, const float* __restrict__ W0,
    const float* __restrict__ b0, const float* __restrict__ wsh,
    const float* __restrict__ Wd, unsigned short* __restrict__ ws) {
  if (blockIdx.x >= 1024) {  // ---- prep path ----
    int i = (blockIdx.x - 1024) * 256 + threadIdx.x;
    if (i < 1152) {  // weight convert+permute: one 16B chunk per thread
      const int o0 = i * 8;
      const int f = o0 / 288;
      const int rem = o0 - f * 288;
      const int tap = rem >> 5;
      const int g = (rem & 31) >> 3;
      unsigned short u[8];
#pragma unroll
      for (int j = 0; j < 8; ++j) {
        const int c = (j < 4) ? 4 * g + j : 16 + 4 * g + (j - 4);
        u[j] = f2bf(wsh[f * 288 + tap * 32 + c]);
      }
      uint4 o;
      o.x = u[0] | ((unsigned)u[1] << 16);
      o.y = u[2] | ((unsigned)u[3] << 16);
      o.z = u[4] | ((unsigned)u[5] << 16);
      o.w = u[6] | ((unsigned)u[7] << 16);
      *(uint4*)(g_wbf + o0) = o;
      return;
    }
    i -= 1152;
    if (i < 12544) {  // each item zeros one 64B chunk of pad cells
      size_t off;
      if (i < 8320) {  // 64-buffers: 4160 items each
        const size_t base = (i < 4160) ? A64e : B64e;
        if (i >= 4160) i -= 4160;
        if (i < 2112) {
          const int b = i / 132, rem = i - b * 132;
          const int rs = rem / 66, ch = rem - rs * 66;
          off = base + (size_t)((b * 66 + (rs ? 65 : 0)) * 66) * 32 + ch * 32;
        } else {
          i -= 2112;
          const int b = i >> 7, rem = i & 127;
          const int r = rem >> 1, side = rem & 1;
          off = base + (size_t)((b * 66 + 1 + r) * 66 + (side ? 65 : 0)) * 32;
        }
      } else {
        i -= 8320;
        const size_t base = (i < 2112) ? A32e : B32e;
        if (i >= 2112) i -= 2112;
        if (i < 1088) {
          const int b = i / 68, rem = i - b * 68;
          const int rs = rem / 34, ch = rem - rs * 34;
          off = base + (size_t)((b * 34 + (rs ? 33 : 0)) * 34) * 32 + ch * 32;
        } else {
          i -= 1088;
          const int b = i >> 6, rem = i & 63;
          const int r = rem >> 1, side = rem & 1;
          off = base + (size_t)((b * 34 + 1 + r) * 34 + (side ? 33 : 0)) * 32;
        }
      }
      uint4* p = (uint4*)(ws + off);
      const uint4 z = {0u, 0u, 0u, 0u};
      p[0] = z; p[1] = z; p[2] = z; p[3] = z;
      return;
    }
    i -= 12544;
    if (i < 131072) {  // Wd2 bf16 [flat 8192][16]: j<10 -> Wd[flat*10+j]
      const int flat = i >> 4, j = i & 15;
      ws[Dne + i] = (j < 10) ? f2bf(Wd[(size_t)flat * 10 + j]) : (unsigned short)0;
      return;
    }
    i -= 131072;
    if (i < 161) ((unsigned*)(ws + LGe))[i] = 0u;  // logits[160] + counter
    return;
  }

  // ---- conv0 path: 8 filters (fg*8..) per thread ----
  const int fg = blockIdx.x & 3;
  const int p = (blockIdx.x >> 2) * 256 + threadIdx.x;
  const int b = p >> 12, rem = p & 4095, h = rem >> 6, w = rem & 63;

  // 9 tap pointers, computed once; OOB -> float zero page
  const float* pt[3][3];
#pragma unroll
  for (int r = 0; r < 3; ++r) {
    const int hh = h - 1 + r;
#pragma unroll
    for (int j = 0; j < 3; ++j) {
      const int col = w - 1 + j;
      const bool ok = ((unsigned)hh < 64u) && ((unsigned)col < 64u);
      pt[r][j] = ok ? in + (((b << 6) + hh) * 64 + col) * 3 : g_zerof;
    }
  }

  float acc[8];
#pragma unroll
  for (int f = 0; f < 8; ++f) acc[f] = b0[fg * 8 + f];  // s_load

#pragma unroll
  for (int dy = 0; dy < 3; ++dy)
#pragma unroll
    for (int dx = 0; dx < 3; ++dx) {
      const float c0 = pt[dy][dx][0];
      const float c1 = pt[dy][dx][1];
      const float c2 = pt[dy][dx][2];
      const float* wp = W0 + ((dy * 3 + dx) * 3) * 32 + fg * 8;  // s_load rows
#pragma unroll
      for (int f = 0; f < 8; ++f)
        acc[f] += c0 * wp[f] + c1 * wp[32 + f] + c2 * wp[64 + f];
    }

  // permuted store: channels fg*8+4q+k -> pos 8*(2*(fg&1)+q) + 4*(fg>>1) + k
  unsigned short* op = ws + A64e + ((size_t)(b * 66 + 1 + h) * 66 + 1 + w) * 32;
  const int hi = fg >> 1;
#pragma unroll
  for (int q = 0; q < 2; ++q) {
    const int pos = 8 * (2 * (fg & 1) + q) + 4 * hi;
    unsigned short u0 = f2bf(fmaxf(acc[4 * q + 0], 0.f));
    unsigned short u1 = f2bf(fmaxf(acc[4 * q + 1], 0.f));
    unsigned short u2 = f2bf(fmaxf(acc[4 * q + 2], 0.f));
    unsigned short u3 = f2bf(fmaxf(acc[4 * q + 3], 0.f));
    uint2 o;
    o.x = u0 | ((unsigned)u1 << 16);
    o.y = u2 | ((unsigned)u3 << 16);
    *(uint2*)(op + pos) = o;
  }
}

// ---------------- MFMA conv 32->32 (+ optional fused pool) ------------------
template <int LGS, bool POOL, bool OPAD>
__global__ __launch_bounds__(256, 4) void conv_mfma(
    const unsigned short* __restrict__ act, const float* __restrict__ bsh,
    unsigned short* __restrict__ outp) {
  constexpr int S = 1 << LGS, PS = S + 2, LGTC = LGS - 4, TC = S >> 4;
  const int wid = __builtin_amdgcn_readfirstlane((int)(threadIdx.x >> 6));
  const int id = blockIdx.x * 4 + wid;
  const int fhalf = id & 1;
  const int tc = (id >> 1) & (TC - 1);
  const int h2 = (id >> (1 + LGTC)) & ((S >> 1) - 1);
  const int b = id >> (LGS + LGTC);
  const int l = (int)(threadIdx.x & 63);
  const int n = l & 15, g = l >> 4;

  const unsigned short* pA = g_wbf + (fhalf * 16 + n) * 288 + 8 * g;
  bf16x8 af[9];
#pragma unroll
  for (int t = 0; t < 9; ++t) af[t] = *(const bf16x8*)(pA + t * 32);

  const unsigned short* pB =
      act + ((size_t)(b * PS + 2 * h2) * PS + tc * 16 + n) * 32 + 8 * g;
  bf16x8 bfr[4][3];
#pragma unroll
  for (int rr = 0; rr < 4; ++rr)
#pragma unroll
    for (int dx = 0; dx < 3; ++dx)
      bfr[rr][dx] = *(const bf16x8*)(pB + (rr * PS + dx) * 32);

  f32x4 acc0 = {0.f, 0.f, 0.f, 0.f};
  f32x4 acc1 = {0.f, 0.f, 0.f, 0.f};
#pragma unroll
  for (int tap = 0; tap < 9; ++tap) {
    const int dy = tap / 3, dx = tap - dy * 3;
    acc0 = __builtin_amdgcn_mfma_f32_16x16x32_bf16(af[tap], bfr[dy][dx], acc0, 0, 0, 0);
    acc1 = __builtin_amdgcn_mfma_f32_16x16x32_bf16(af[tap], bfr[dy + 1][dx], acc1, 0, 0, 0);
  }

  const float4 bias = *(const float4*)(bsh + fhalf * 16 + 4 * g);
  const float bv[4] = {bias.x, bias.y, bias.z, bias.w};
  const int opos = 8 * g + 4 * fhalf;

  if (!POOL) {
#pragma unroll
    for (int t = 0; t < 2; ++t) {
      unsigned short u[4];
#pragma unroll
      for (int r = 0; r < 4; ++r) {
        const float a = (t == 0) ? acc0[r] : acc1[r];
        u[r] = f2bf(fmaxf(a + bv[r], 0.f));
      }
      uint2 o;
      o.x = u[0] | ((unsigned)u[1] << 16);
      o.y = u[2] | ((unsigned)u[3] << 16);
      unsigned short* op = outp +
          ((size_t)(b * PS + 2 * h2 + 1 + t) * PS + 1 + tc * 16 + n) * 32 + opos;
      *(uint2*)op = o;
    }
  } else {
    float m[4];
#pragma unroll
    for (int r = 0; r < 4; ++r) {
      const float v0 = fmaxf(acc0[r] + bv[r], 0.f);
      const float v1 = fmaxf(acc1[r] + bv[r], 0.f);
      m[r] = fmaxf(v0, v1);
      m[r] = fmaxf(m[r], __shfl_xor(m[r], 1, 64));
    }
    if (!(n & 1)) {
      unsigned short u[4];
#pragma unroll
      for (int r = 0; r < 4; ++r) u[r] = f2bf(m[r]);
      uint2 o;
      o.x = u[0] | ((unsigned)u[1] << 16);
      o.y = u[2] | ((unsigned)u[3] << 16);
      unsigned short* op =
          outp + ((size_t)(b * 34 + 1 + h2) * 34 + 1 + tc * 8 + (n >> 1)) * 32 + opos;
      *(uint2*)op = o;
    }
  }
}

// ------ conv4 + pool + dense partial + (last block) softmax -----------------
// Same geometry as conv_mfma<5,true,...>: 256 blocks x 4 waves, 1 unit/wave;
// all 4 waves of a block share one image (id bits: [b][h2][tc][fhalf]).
__global__ __launch_bounds__(256, 4) void conv4_dense(
    const unsigned short* __restrict__ act, const float* __restrict__ bsh,
    const unsigned short* __restrict__ wd2, const float* __restrict__ bd,
    float* __restrict__ logits, int* __restrict__ cnt,
    float* __restrict__ out) {
  constexpr int PS = 34;
  const int wid = __builtin_amdgcn_readfirstlane((int)(threadIdx.x >> 6));
  const int id = blockIdx.x * 4 + wid;
  const int fhalf = id & 1;
  const int tc = (id >> 1) & 1;
  const int h2 = (id >> 2) & 15;
  const int b = id >> 6;
  const int l = (int)(threadIdx.x & 63);
  const int n = l & 15, g = l >> 4;

  const unsigned short* pA = g_wbf + (fhalf * 16 + n) * 288 + 8 * g;
  bf16x8 af[9];
#pragma unroll
  for (int t = 0; t < 9; ++t) af[t] = *(const bf16x8*)(pA + t * 32);

  const unsigned short* pB =
      act + ((size_t)(b * PS + 2 * h2) * PS + tc * 16 + n) * 32 + 8 * g;
  bf16x8 bfr[4][3];
#pragma unroll
  for (int rr = 0; rr < 4; ++rr)
#pragma unroll
    for (int dx = 0; dx < 3; ++dx)
      bfr[rr][dx] = *(const bf16x8*)(pB + (rr * PS + dx) * 32);

  f32x4 acc0 = {0.f, 0.f, 0.f, 0.f};
  f32x4 acc1 = {0.f, 0.f, 0.f, 0.f};
#pragma unroll
  for (int tap = 0; tap < 9; ++tap) {
    const int dy = tap / 3, dx = tap - dy * 3;
    acc0 = __builtin_amdgcn_mfma_f32_16x16x32_bf16(af[tap], bfr[dy][dx], acc0, 0, 0, 0);
    acc1 = __builtin_amdgcn_mfma_f32_16x16x32_bf16(af[tap], bfr[dy + 1][dx], acc1, 0, 0, 0);
  }

  const float4 bias = *(const float4*)(bsh + fhalf * 16 + 4 * g);
  const float bv[4] = {bias.x, bias.y, bias.z, bias.w};

  float m[4];
#pragma unroll
  for (int r = 0; r < 4; ++r) {
    const float v0 = fmaxf(acc0[r] + bv[r], 0.f);
    const float v1 = fmaxf(acc1[r] + bv[r], 0.f);
    m[r] = fmaxf(v0, v1);
    m[r] = fmaxf(m[r], __shfl_xor(m[r], 1, 64));
  }

  // ---- dense partial: even lanes own pool px (h2, tc*8+n/2), ch 4g..+3 ----
  float dacc[10];
#pragma unroll
  for (int j = 0; j < 10; ++j) dacc[j] = 0.f;
  if (!(n & 1)) {
    const int flat0 = ((h2 * 16) + tc * 8 + (n >> 1)) * 32 + fhalf * 16 + 4 * g;
    const unsigned short* wr0 = wd2 + (size_t)flat0 * 16;
#pragma unroll
    for (int r = 0; r < 4; ++r) {
      const unsigned short* wr = wr0 + r * 16;
      const bf16x8 w0 = *(const bf16x8*)wr;          // j 0..7
      const unsigned w1 = *(const unsigned*)(wr + 8);  // j 8..9
      const float xv = m[r];
#pragma unroll
      for (int j = 0; j < 8; ++j) dacc[j] += xv * bf2f((unsigned short)w0[j]);
      dacc[8] += xv * bf2f((unsigned short)(w1 & 0xffffu));
      dacc[9] += xv * bf2f((unsigned short)(w1 >> 16));
    }
  }
  // wave reduce (odd lanes contribute 0)
#pragma unroll
  for (int off = 32; off > 0; off >>= 1)
#pragma unroll
    for (int j = 0; j < 10; ++j) dacc[j] += __shfl_xor(dacc[j], off, 64);

  __shared__ float red[4][10];
  __shared__ float sm[160];
  __shared__ int lastflag;
  if (l == 0) {
#pragma unroll
    for (int j = 0; j < 10; ++j) red[wid][j] = dacc[j];
  }
  __syncthreads();
  const int tid = (int)threadIdx.x;
  if (tid < 10) {
    const float s = red[0][tid] + red[1][tid] + red[2][tid] + red[3][tid];
    atomicAdd(logits + b * 10 + tid, s);
    __threadfence();
  }
  __syncthreads();
  if (tid == 0) {
    const int old = atomicAdd(cnt, 1);
    lastflag = (old == 255) ? 1 : 0;
  }
  __syncthreads();

  if (lastflag) {
    if (tid < 160) {
      const int j = tid - (tid / 10) * 10;
      sm[tid] = atomicAdd(logits + tid, 0.f) + bd[j];
    }
    __syncthreads();
    if (tid < 16) {
      float lg[10];
      float mx = -1e30f;
#pragma unroll
      for (int j = 0; j < 10; ++j) {
        lg[j] = sm[tid * 10 + j];
        mx = fmaxf(mx, lg[j]);
      }
      float s = 0.f;
#pragma unroll
      for (int j = 0; j < 10; ++j) {
        lg[j] = expf(lg[j] - mx);
        s += lg[j];
      }
      const float inv = 1.f / s;
#pragma unroll
      for (int j = 0; j < 10; ++j) out[tid * 10 + j] = lg[j] * inv;
    }
  }
}

extern "C" void kernel_launch(void* const* d_in, const int* in_sizes, int n_in,
                              void* d_out, int out_size, void* d_ws, size_t ws_size,
                              hipStream_t stream) {
  const float* in = (const float*)d_in[0];
  const float* W0 = (const float*)d_in[1];
  const float* b0 = (const float*)d_in[2];
  const float* wsh = (const float*)d_in[3];
  const float* bsh = (const float*)d_in[4];
  const float* Wd = (const float*)d_in[5];
  const float* bd = (const float*)d_in[6];
  float* out = (float*)d_out;

  unsigned short* ws = (unsigned short*)d_ws;
  unsigned short* A64 = ws + A64e;
  unsigned short* B64 = ws + B64e;
  unsigned short* A32 = ws + A32e;
  unsigned short* B32 = ws + B32e;
  unsigned short* Wd2 = ws + Dne;
  float* logits = (float*)(ws + LGe);
  int* cnt = (int*)(logits + 160);

  conv0_prep<<<1591, 256, 0, stream>>>(in, W0, b0, wsh, Wd, ws);
  conv_mfma<6, false, false><<<1024, 256, 0, stream>>>(A64, bsh, B64);  // conv1
  conv_mfma<6, true, true><<<1024, 256, 0, stream>>>(B64, bsh, A32);    // conv2+pool
  conv_mfma<5, false, false><<<256, 256, 0, stream>>>(A32, bsh, B32);   // conv3
  conv4_dense<<<256, 256, 0, stream>>>(B32, bsh, Wd2, bd, logits, cnt, out);
}

// Round 13
// 37.191 us; speedup vs baseline: 1.4677x; 1.1149x over previous
//
#include <hip/hip_runtime.h>
#include <math.h>

// Dims: B=16, H=64, W=64, Cin=3, F=32, K=3
// 5 launches: conv0+prep | conv1 | conv2+pool | conv3 | conv4+pool+dense+softmax.
// Convs 1-4: bf16 MFMA 16x16x32, A=weights(16 filters), B=activations(16 px),
// K=288; PERMUTED channel layout pi (pos 8g+j <-> ch j<4?4g+j:16+4g+j-4) so
// every frag is ONE 16B load; contraction cancels pi (A,B share k-order).
// Activations zero-padded [16][S+2][S+2][32] bf16 -> unconditional halo loads.
// NEW (R13): XCD-affinity blockIdx swizzle in EVERY kernel. Work ids are
// image-major, so wb=(bid&7)*(nwg/8)+(bid>>3) gives each XCD a contiguous
// chunk = 2 images at every layer -> 2.2MB working set fits the 4MB per-XCD
// L2, and layer k's output is L2-resident for layer k+1 (same mapping).

typedef __attribute__((ext_vector_type(8))) short bf16x8;
typedef __attribute__((ext_vector_type(4))) float f32x4;

__device__ __align__(16) unsigned short g_wbf[32 * 288];  // bf16 [f][tap*32+pos]
__device__ __align__(64) float g_zerof[16];               // zero page (floats)

// ---- workspace layout (ushort elems) ----
#define A64e ((size_t)0)
#define B64e ((size_t)(16 * 66 * 66 * 32))            // 2,230,272
#define A32e ((size_t)(2 * 16 * 66 * 66 * 32))        // 4,460,544
#define B32e (A32e + (size_t)(16 * 34 * 34 * 32))     // 5,052,416
#define Dne  (B32e + (size_t)(16 * 34 * 34 * 32))     // Wd2 bf16 [8192][16]
#define LGe  (Dne + (size_t)131072)                   // logits f32[160] + cnt

__device__ __forceinline__ unsigned short f2bf(float x) {
  union { float f; unsigned u; } v;
  v.f = x;
  return (unsigned short)((v.u + 0x7FFFu + ((v.u >> 16) & 1u)) >> 16);
}
__device__ __forceinline__ float bf2f(unsigned short x) {
  union { unsigned u; float f; } v;
  v.u = ((unsigned)x) << 16;
  return v.f;
}
// XCD-affinity swizzle: hw round-robins bid%8 across XCDs; give each XCD a
// contiguous chunk of image-major work ids. nwg must be divisible by 8.
__device__ __forceinline__ int swz_bid(int bid, int nwg) {
  return (bid & 7) * (nwg >> 3) + (bid >> 3);
}

// ---------------- fused prep + conv0 ----------------------------------------
// blocks 0..1023: conv0 (swizzled; fg = wb&3, 8 filters each).
// blocks 1024+: w convert+permute (1152) | pad zero (12544) | Wd2 (131072) |
// logits+cnt zero (161).
__global__ __launch_bounds__(256) void conv0_prep(
    const float* __restrict__ in, const float* __restrict__ W0,
    const float* __restrict__ b0, const float* __restrict__ wsh,
    const float* __restrict__ Wd, unsigned short* __restrict__ ws) {
  if (blockIdx.x >= 1024) {  // ---- prep path ----
    int i = (blockIdx.x - 1024) * 256 + threadIdx.x;
    if (i < 1152) {  // weight convert+permute: one 16B chunk per thread
      const int o0 = i * 8;
      const int f = o0 / 288;
      const int rem = o0 - f * 288;
      const int tap = rem >> 5;
      const int g = (rem & 31) >> 3;
      unsigned short u[8];
#pragma unroll
      for (int j = 0; j < 8; ++j) {
        const int c = (j < 4) ? 4 * g + j : 16 + 4 * g + (j - 4);
        u[j] = f2bf(wsh[f * 288 + tap * 32 + c]);
      }
      uint4 o;
      o.x = u[0] | ((unsigned)u[1] << 16);
      o.y = u[2] | ((unsigned)u[3] << 16);
      o.z = u[4] | ((unsigned)u[5] << 16);
      o.w = u[6] | ((unsigned)u[7] << 16);
      *(uint4*)(g_wbf + o0) = o;
      return;
    }
    i -= 1152;
    if (i < 12544) {  // each item zeros one 64B chunk of pad cells
      size_t off;
      if (i < 8320) {  // 64-buffers: 4160 items each
        const size_t base = (i < 4160) ? A64e : B64e;
        if (i >= 4160) i -= 4160;
        if (i < 2112) {
          const int b = i / 132, rem = i - b * 132;
          const int rs = rem / 66, ch = rem - rs * 66;
          off = base + (size_t)((b * 66 + (rs ? 65 : 0)) * 66) * 32 + ch * 32;
        } else {
          i -= 2112;
          const int b = i >> 7, rem = i & 127;
          const int r = rem >> 1, side = rem & 1;
          off = base + (size_t)((b * 66 + 1 + r) * 66 + (side ? 65 : 0)) * 32;
        }
      } else {
        i -= 8320;
        const size_t base = (i < 2112) ? A32e : B32e;
        if (i >= 2112) i -= 2112;
        if (i < 1088) {
          const int b = i / 68, rem = i - b * 68;
          const int rs = rem / 34, ch = rem - rs * 34;
          off = base + (size_t)((b * 34 + (rs ? 33 : 0)) * 34) * 32 + ch * 32;
        } else {
          i -= 1088;
          const int b = i >> 6, rem = i & 63;
          const int r = rem >> 1, side = rem & 1;
          off = base + (size_t)((b * 34 + 1 + r) * 34 + (side ? 33 : 0)) * 32;
        }
      }
      uint4* p = (uint4*)(ws + off);
      const uint4 z = {0u, 0u, 0u, 0u};
      p[0] = z; p[1] = z; p[2] = z; p[3] = z;
      return;
    }
    i -= 12544;
    if (i < 131072) {  // Wd2 bf16 [flat 8192][16]: j<10 -> Wd[flat*10+j]
      const int flat = i >> 4, j = i & 15;
      ws[Dne + i] = (j < 10) ? f2bf(Wd[(size_t)flat * 10 + j]) : (unsigned short)0;
      return;
    }
    i -= 131072;
    if (i < 161) ((unsigned*)(ws + LGe))[i] = 0u;  // logits[160] + counter
    return;
  }

  // ---- conv0 path: 8 filters (fg*8..) per thread ----
  const int wb = swz_bid((int)blockIdx.x, 1024);
  const int fg = wb & 3;
  const int p = (wb >> 2) * 256 + threadIdx.x;
  const int b = p >> 12, rem = p & 4095, h = rem >> 6, w = rem & 63;

  // 9 tap pointers, computed once; OOB -> float zero page
  const float* pt[3][3];
#pragma unroll
  for (int r = 0; r < 3; ++r) {
    const int hh = h - 1 + r;
#pragma unroll
    for (int j = 0; j < 3; ++j) {
      const int col = w - 1 + j;
      const bool ok = ((unsigned)hh < 64u) && ((unsigned)col < 64u);
      pt[r][j] = ok ? in + (((b << 6) + hh) * 64 + col) * 3 : g_zerof;
    }
  }

  float acc[8];
#pragma unroll
  for (int f = 0; f < 8; ++f) acc[f] = b0[fg * 8 + f];  // s_load

#pragma unroll
  for (int dy = 0; dy < 3; ++dy)
#pragma unroll
    for (int dx = 0; dx < 3; ++dx) {
      const float c0 = pt[dy][dx][0];
      const float c1 = pt[dy][dx][1];
      const float c2 = pt[dy][dx][2];
      const float* wp = W0 + ((dy * 3 + dx) * 3) * 32 + fg * 8;  // s_load rows
#pragma unroll
      for (int f = 0; f < 8; ++f)
        acc[f] += c0 * wp[f] + c1 * wp[32 + f] + c2 * wp[64 + f];
    }

  // permuted store: channels fg*8+4q+k -> pos 8*(2*(fg&1)+q) + 4*(fg>>1) + k
  unsigned short* op = ws + A64e + ((size_t)(b * 66 + 1 + h) * 66 + 1 + w) * 32;
  const int hi = fg >> 1;
#pragma unroll
  for (int q = 0; q < 2; ++q) {
    const int pos = 8 * (2 * (fg & 1) + q) + 4 * hi;
    unsigned short u0 = f2bf(fmaxf(acc[4 * q + 0], 0.f));
    unsigned short u1 = f2bf(fmaxf(acc[4 * q + 1], 0.f));
    unsigned short u2 = f2bf(fmaxf(acc[4 * q + 2], 0.f));
    unsigned short u3 = f2bf(fmaxf(acc[4 * q + 3], 0.f));
    uint2 o;
    o.x = u0 | ((unsigned)u1 << 16);
    o.y = u2 | ((unsigned)u3 << 16);
    *(uint2*)(op + pos) = o;
  }
}

// ---------------- MFMA conv 32->32 (+ optional fused pool) ------------------
template <int LGS, bool POOL, bool OPAD>
__global__ __launch_bounds__(256, 4) void conv_mfma(
    const unsigned short* __restrict__ act, const float* __restrict__ bsh,
    unsigned short* __restrict__ outp) {
  constexpr int S = 1 << LGS, PS = S + 2, LGTC = LGS - 4, TC = S >> 4;
  constexpr int NB = (16 * (S >> 1) * TC * 2) / 4;  // grid size
  const int wb = swz_bid((int)blockIdx.x, NB);
  const int wid = __builtin_amdgcn_readfirstlane((int)(threadIdx.x >> 6));
  const int id = wb * 4 + wid;
  const int fhalf = id & 1;
  const int tc = (id >> 1) & (TC - 1);
  const int h2 = (id >> (1 + LGTC)) & ((S >> 1) - 1);
  const int b = id >> (LGS + LGTC);
  const int l = (int)(threadIdx.x & 63);
  const int n = l & 15, g = l >> 4;

  const unsigned short* pA = g_wbf + (fhalf * 16 + n) * 288 + 8 * g;
  bf16x8 af[9];
#pragma unroll
  for (int t = 0; t < 9; ++t) af[t] = *(const bf16x8*)(pA + t * 32);

  const unsigned short* pB =
      act + ((size_t)(b * PS + 2 * h2) * PS + tc * 16 + n) * 32 + 8 * g;
  bf16x8 bfr[4][3];
#pragma unroll
  for (int rr = 0; rr < 4; ++rr)
#pragma unroll
    for (int dx = 0; dx < 3; ++dx)
      bfr[rr][dx] = *(const bf16x8*)(pB + (rr * PS + dx) * 32);

  f32x4 acc0 = {0.f, 0.f, 0.f, 0.f};
  f32x4 acc1 = {0.f, 0.f, 0.f, 0.f};
#pragma unroll
  for (int tap = 0; tap < 9; ++tap) {
    const int dy = tap / 3, dx = tap - dy * 3;
    acc0 = __builtin_amdgcn_mfma_f32_16x16x32_bf16(af[tap], bfr[dy][dx], acc0, 0, 0, 0);
    acc1 = __builtin_amdgcn_mfma_f32_16x16x32_bf16(af[tap], bfr[dy + 1][dx], acc1, 0, 0, 0);
  }

  const float4 bias = *(const float4*)(bsh + fhalf * 16 + 4 * g);
  const float bv[4] = {bias.x, bias.y, bias.z, bias.w};
  const int opos = 8 * g + 4 * fhalf;

  if (!POOL) {
#pragma unroll
    for (int t = 0; t < 2; ++t) {
      unsigned short u[4];
#pragma unroll
      for (int r = 0; r < 4; ++r) {
        const float a = (t == 0) ? acc0[r] : acc1[r];
        u[r] = f2bf(fmaxf(a + bv[r], 0.f));
      }
      uint2 o;
      o.x = u[0] | ((unsigned)u[1] << 16);
      o.y = u[2] | ((unsigned)u[3] << 16);
      unsigned short* op = outp +
          ((size_t)(b * PS + 2 * h2 + 1 + t) * PS + 1 + tc * 16 + n) * 32 + opos;
      *(uint2*)op = o;
    }
  } else {
    float m[4];
#pragma unroll
    for (int r = 0; r < 4; ++r) {
      const float v0 = fmaxf(acc0[r] + bv[r], 0.f);
      const float v1 = fmaxf(acc1[r] + bv[r], 0.f);
      m[r] = fmaxf(v0, v1);
      m[r] = fmaxf(m[r], __shfl_xor(m[r], 1, 64));
    }
    if (!(n & 1)) {
      unsigned short u[4];
#pragma unroll
      for (int r = 0; r < 4; ++r) u[r] = f2bf(m[r]);
      uint2 o;
      o.x = u[0] | ((unsigned)u[1] << 16);
      o.y = u[2] | ((unsigned)u[3] << 16);
      unsigned short* op =
          outp + ((size_t)(b * 34 + 1 + h2) * 34 + 1 + tc * 8 + (n >> 1)) * 32 + opos;
      *(uint2*)op = o;
    }
  }
}

// ------ conv4 + pool + dense partial + (last block) softmax -----------------
__global__ __launch_bounds__(256, 4) void conv4_dense(
    const unsigned short* __restrict__ act, const float* __restrict__ bsh,
    const unsigned short* __restrict__ wd2, const float* __restrict__ bd,
    float* __restrict__ logits, int* __restrict__ cnt,
    float* __restrict__ out) {
  constexpr int PS = 34;
  const int wb = swz_bid((int)blockIdx.x, 256);
  const int wid = __builtin_amdgcn_readfirstlane((int)(threadIdx.x >> 6));
  const int id = wb * 4 + wid;
  const int fhalf = id & 1;
  const int tc = (id >> 1) & 1;
  const int h2 = (id >> 2) & 15;
  const int b = id >> 6;
  const int l = (int)(threadIdx.x & 63);
  const int n = l & 15, g = l >> 4;

  const unsigned short* pA = g_wbf + (fhalf * 16 + n) * 288 + 8 * g;
  bf16x8 af[9];
#pragma unroll
  for (int t = 0; t < 9; ++t) af[t] = *(const bf16x8*)(pA + t * 32);

  const unsigned short* pB =
      act + ((size_t)(b * PS + 2 * h2) * PS + tc * 16 + n) * 32 + 8 * g;
  bf16x8 bfr[4][3];
#pragma unroll
  for (int rr = 0; rr < 4; ++rr)
#pragma unroll
    for (int dx = 0; dx < 3; ++dx)
      bfr[rr][dx] = *(const bf16x8*)(pB + (rr * PS + dx) * 32);

  f32x4 acc0 = {0.f, 0.f, 0.f, 0.f};
  f32x4 acc1 = {0.f, 0.f, 0.f, 0.f};
#pragma unroll
  for (int tap = 0; tap < 9; ++tap) {
    const int dy = tap / 3, dx = tap - dy * 3;
    acc0 = __builtin_amdgcn_mfma_f32_16x16x32_bf16(af[tap], bfr[dy][dx], acc0, 0, 0, 0);
    acc1 = __builtin_amdgcn_mfma_f32_16x16x32_bf16(af[tap], bfr[dy + 1][dx], acc1, 0, 0, 0);
  }

  const float4 bias = *(const float4*)(bsh + fhalf * 16 + 4 * g);
  const float bv[4] = {bias.x, bias.y, bias.z, bias.w};

  float m[4];
#pragma unroll
  for (int r = 0; r < 4; ++r) {
    const float v0 = fmaxf(acc0[r] + bv[r], 0.f);
    const float v1 = fmaxf(acc1[r] + bv[r], 0.f);
    m[r] = fmaxf(v0, v1);
    m[r] = fmaxf(m[r], __shfl_xor(m[r], 1, 64));
  }

  // ---- dense partial: even lanes own pool px (h2, tc*8+n/2), ch 4g..+3 ----
  float dacc[10];
#pragma unroll
  for (int j = 0; j < 10; ++j) dacc[j] = 0.f;
  if (!(n & 1)) {
    const int flat0 = ((h2 * 16) + tc * 8 + (n >> 1)) * 32 + fhalf * 16 + 4 * g;
    const unsigned short* wr0 = wd2 + (size_t)flat0 * 16;
#pragma unroll
    for (int r = 0; r < 4; ++r) {
      const unsigned short* wr = wr0 + r * 16;
      const bf16x8 w0 = *(const bf16x8*)wr;            // j 0..7
      const unsigned w1 = *(const unsigned*)(wr + 8);  // j 8..9
      const float xv = m[r];
#pragma unroll
      for (int j = 0; j < 8; ++j) dacc[j] += xv * bf2f((unsigned short)w0[j]);
      dacc[8] += xv * bf2f((unsigned short)(w1 & 0xffffu));
      dacc[9] += xv * bf2f((unsigned short)(w1 >> 16));
    }
  }
#pragma unroll
  for (int off = 32; off > 0; off >>= 1)
#pragma unroll
    for (int j = 0; j < 10; ++j) dacc[j] += __shfl_xor(dacc[j], off, 64);

  __shared__ float red[4][10];
  __shared__ float sm[160];
  __shared__ int lastflag;
  if (l == 0) {
#pragma unroll
    for (int j = 0; j < 10; ++j) red[wid][j] = dacc[j];
  }
  __syncthreads();
  const int tid = (int)threadIdx.x;
  if (tid < 10) {
    const float s = red[0][tid] + red[1][tid] + red[2][tid] + red[3][tid];
    atomicAdd(logits + b * 10 + tid, s);
    __threadfence();
  }
  __syncthreads();
  if (tid == 0) {
    const int old = atomicAdd(cnt, 1);
    lastflag = (old == 255) ? 1 : 0;
  }
  __syncthreads();

  if (lastflag) {
    if (tid < 160) {
      const int j = tid - (tid / 10) * 10;
      sm[tid] = atomicAdd(logits + tid, 0.f) + bd[j];
    }
    __syncthreads();
    if (tid < 16) {
      float lg[10];
      float mx = -1e30f;
#pragma unroll
      for (int j = 0; j < 10; ++j) {
        lg[j] = sm[tid * 10 + j];
        mx = fmaxf(mx, lg[j]);
      }
      float s = 0.f;
#pragma unroll
      for (int j = 0; j < 10; ++j) {
        lg[j] = expf(lg[j] - mx);
        s += lg[j];
      }
      const float inv = 1.f / s;
#pragma unroll
      for (int j = 0; j < 10; ++j) out[tid * 10 + j] = lg[j] * inv;
    }
  }
}

extern "C" void kernel_launch(void* const* d_in, const int* in_sizes, int n_in,
                              void* d_out, int out_size, void* d_ws, size_t ws_size,
                              hipStream_t stream) {
  const float* in = (const float*)d_in[0];
  const float* W0 = (const float*)d_in[1];
  const float* b0 = (const float*)d_in[2];
  const float* wsh = (const float*)d_in[3];
  const float* bsh = (const float*)d_in[4];
  const float* Wd = (const float*)d_in[5];
  const float* bd = (const float*)d_in[6];
  float* out = (float*)d_out;

  unsigned short* ws = (unsigned short*)d_ws;
  unsigned short* A64 = ws + A64e;
  unsigned short* B64 = ws + B64e;
  unsigned short* A32 = ws + A32e;
  unsigned short* B32 = ws + B32e;
  unsigned short* Wd2 = ws + Dne;
  float* logits = (float*)(ws + LGe);
  int* cnt = (int*)(logits + 160);

  conv0_prep<<<1591, 256, 0, stream>>>(in, W0, b0, wsh, Wd, ws);
  conv_mfma<6, false, false><<<1024, 256, 0, stream>>>(A64, bsh, B64);  // conv1
  conv_mfma<6, true, true><<<1024, 256, 0, stream>>>(B64, bsh, A32);    // conv2+pool
  conv_mfma<5, false, false><<<256, 256, 0, stream>>>(A32, bsh, B32);   // conv3
  conv4_dense<<<256, 256, 0, stream>>>(B32, bsh, Wd2, bd, logits, cnt, out);
}